// Round 7
// baseline (2823.730 us; speedup 1.0000x reference)
//
#include <hip/hip_runtime.h>
#include <stdint.h>

// LSTM: B=65536, T=28, IN=28, H=128. Final hidden [B,H] output.
// ROUND 7: R6 structure (8-wave/512-thread blocks, wave owns 16 cols x 4
// gates, weights persistent in registers) + occupancy doubled:
//  - c back in REGISTERS (8/thread; R6 showed VGPR=64, tons of headroom)
//  - LDS 39424 -> 22528 B (c_lds gone) -> 7 blocks/CU by LDS
//  - __launch_bounds__(512, 8): 8 waves/EU = 32 waves/CU = 4 blocks resident
//    (R6 ran ~2 blocks / 43% occupancy; VALUBusy 60% = latency-bound).
// Unified reg budget at 8 waves/EU = 256/wave; live ~155 (80 wgt AGPR +
// 16 acc + 8 c + 8 a + temps) -> no spill (watch WRITE_SIZE ~= output only).
// Lessons kept: no volatile-asm reg pins (R5, 2.3x regression); weights
// persistent beats L2 streaming (R6 vs R1-R4).

#define T_STEPS   28
#define HDIM      128
#define KIN       156            // H + IN
#define MB        32             // batch rows per block
#define KSTEPS    5              // K=160: 4x32 (h) + 1x32 (x: 28 real + 4 pad)
#define HLDS_ST   136            // h_lds row stride in shorts (128 + 8 pad)
#define XLDS_ST   40             // x_lds row stride in shorts (32 + 8 pad)

#define WS_WOFF   1024                       // byte offset of packed weights in d_ws
#define WS_BOFF   (1024 + 4*HDIM*160*2)      // byte offset of fp32 biases

typedef __attribute__((ext_vector_type(8))) short  short8;
typedef __attribute__((ext_vector_type(4))) float  floatx4;

union Frag { short8 f; uint2 u2[2]; unsigned short s[8]; };
union Pk4  { uint2 u2; unsigned short s[4]; };

__device__ __forceinline__ float bf2f(unsigned short v) {
    union { uint32_t u; float f; } c; c.u = ((uint32_t)v) << 16; return c.f;
}
__device__ __forceinline__ unsigned short f2bf(float x) {
    union { float f; uint32_t u; } c; c.f = x;          // RNE bf16 (finite inputs)
    return (unsigned short)((c.u + 0x7FFFu + ((c.u >> 16) & 1u)) >> 16);
}
__device__ __forceinline__ float fast_rcp(float x) { return __builtin_amdgcn_rcpf(x); }
// NaN-free at extremes: exp->inf => rcp->0; exp->0 => rcp(1)=1.
__device__ __forceinline__ float sigm(float x)   { return fast_rcp(1.0f + __expf(-x)); }
__device__ __forceinline__ float tanh_f(float x) {
    float e = __expf(2.0f * x);
    return 1.0f - 2.0f * fast_rcp(e + 1.0f);
}

// bf16 |W_f| <= 0.08 -> exponent field <= 123 always. fp32 read as shorts:
// mantissa halves ~uniform -> exponent field >= 127 with p~0.5/short.
__global__ void detect_dtype(const unsigned short* __restrict__ wf, int* __restrict__ flag) {
    const int lane = threadIdx.x;
    bool big = false;
    #pragma unroll
    for (int i = 0; i < 4; ++i) {
        unsigned e = (wf[lane * 4 + i] >> 7) & 0xFFu;
        if (e >= 127u) big = true;
    }
    const int isfp32 = __any(big) ? 1 : 0;
    if (lane == 0) *flag = isfp32;
}

// One-shot: pack W[4][128][156] -> bf16 per-(wave,ks,lane) fragments:
//   chunk = wv*5+ks (2048 shorts each); within: lane(6b), g(2b), e(3b)
//   value = W[g][wv*16 + (lane&15)][ks*32 + (lane>>4)*8 + e]  (0 beyond K=156)
// Biases -> fp32 [4][128]. Grid: 320 x 256 = 81920 shorts.
template <bool FP32>
__global__ void pack_weights(const void* __restrict__ Wf_, const void* __restrict__ bf_,
                             const void* __restrict__ Wi_, const void* __restrict__ bi_,
                             const void* __restrict__ Wc_, const void* __restrict__ bc_,
                             const void* __restrict__ Wo_, const void* __restrict__ bo_,
                             void* __restrict__ ws, const int* __restrict__ flag)
{
    if (*flag != (FP32 ? 1 : 0)) return;
    unsigned short* wpk = (unsigned short*)((char*)ws + WS_WOFF);
    float*          bpk = (float*)((char*)ws + WS_BOFF);

    const int gid = blockIdx.x * 256 + threadIdx.x;        // 0..81919
    const int e   = gid & 7;
    const int g   = (gid >> 3) & 3;
    const int ln  = (gid >> 5) & 63;
    const int blk = gid >> 11;                             // wv*5 + ks, 0..39
    const int ks  = blk % KSTEPS;
    const int wv  = blk / KSTEPS;
    const int n   = wv * 16 + (ln & 15);
    const int k   = ks * 32 + (ln >> 4) * 8 + e;
    const void* Wg = (g == 0) ? Wf_ : (g == 1) ? Wi_ : (g == 2) ? Wc_ : Wo_;

    unsigned short v = 0;
    if (k < KIN) {
        if constexpr (FP32) v = f2bf(((const float*)Wg)[n * KIN + k]);
        else                v = ((const unsigned short*)Wg)[n * KIN + k];
    }
    wpk[gid] = v;

    if (gid < 4 * HDIM) {
        const int gg = gid >> 7, nn = gid & 127;
        const void* bg = (gg == 0) ? bf_ : (gg == 1) ? bi_ : (gg == 2) ? bc_ : bo_;
        if constexpr (FP32) bpk[gid] = ((const float*)bg)[nn];
        else                bpk[gid] = bf2f(((const unsigned short*)bg)[nn]);
    }
}

template <bool FP32>
__global__ __launch_bounds__(512, 8)
void lstm_fused(const void* __restrict__ x_, const void* __restrict__ ws,
                void* __restrict__ out_, const int* __restrict__ flag)
{
    if (*flag != (FP32 ? 1 : 0)) return;   // wrong-dtype variant: uniform exit

    __shared__ __align__(16) unsigned short h_lds[2][MB * HLDS_ST];   // 17408 B
    __shared__ __align__(16) unsigned short x_lds[2][MB * XLDS_ST];   //  5120 B

    const int tid  = threadIdx.x;
    const int wv   = tid >> 6;     // wave 0..7: owns output cols [16wv, 16wv+16)
    const int lane = tid & 63;
    const int q    = lane >> 4;    // quad
    const int cc   = lane & 15;
    const int b0   = blockIdx.x * MB;

    const unsigned short* wpk = (const unsigned short*)((const char*)ws + WS_WOFF);
    const float*          bpk = (const float*)((const char*)ws + WS_BOFF);

    // ---- persistent weight B-fragments: 4 gates x 5 ks x 4 regs = 80.
    // Loaded once from L2 (20 x dwordx4 per thread); zero in-loop traffic.
    Frag bfr[4][KSTEPS];
    #pragma unroll
    for (int ks = 0; ks < KSTEPS; ++ks)
        #pragma unroll
        for (int g = 0; g < 4; ++g)
            bfr[g][ks].f = *(const short8*)(wpk + (size_t)(wv * KSTEPS + ks) * 2048
                                                + lane * 32 + g * 8);

    float bias_r[4];
    #pragma unroll
    for (int g = 0; g < 4; ++g)
        bias_r[g] = bpk[g * HDIM + wv * 16 + cc];

    // zero h buf0 (h0=0), x pads (shorts 28..39 stay 0 forever)
    for (int i = tid; i < MB * HLDS_ST; i += 512) h_lds[0][i] = 0;
    for (int i = tid; i < MB * XLDS_ST; i += 512) { x_lds[0][i] = 0; x_lds[1][i] = 0; }

    // x staging: 7 threads/row, 4 elems each -> 28 elems/row (224 of 512 threads)
    auto stage_x = [&](int ts, int buf) {
        if (tid < 224) {
            const int row = tid / 7, sub = tid % 7;
            const size_t off = (size_t)(b0 + row) * (T_STEPS * 28) + ts * 28 + sub * 4;
            Pk4 pk;
            if constexpr (FP32) {
                float4 v = *(const float4*)((const float*)x_ + off);
                pk.s[0] = f2bf(v.x); pk.s[1] = f2bf(v.y);
                pk.s[2] = f2bf(v.z); pk.s[3] = f2bf(v.w);
            } else {
                pk.u2 = *(const uint2*)((const unsigned short*)x_ + off);
            }
            *(uint2*)&x_lds[buf][row * XLDS_ST + sub * 4] = pk.u2;
        }
    };
    stage_x(0, 0);

    // ---- cell state in registers: thread owns col j = wv*16+cc, rows
    // mrow = mt*16 + q*4 + r -> c_st[mt][r], 8 VGPRs.
    float c_st[2][4];
    #pragma unroll
    for (int mt = 0; mt < 2; ++mt)
        #pragma unroll
        for (int r = 0; r < 4; ++r) c_st[mt][r] = 0.0f;

    __syncthreads();

    int cur = 0;
    #pragma unroll 1
    for (int t = 0; t < T_STEPS; ++t) {
        // prefetch next x tile into the other buffer (no reader until next step)
        if (t + 1 < T_STEPS) stage_x(t + 1, cur ^ 1);

        #pragma unroll
        for (int mt = 0; mt < 2; ++mt) {
            // A fragments: parity double-buffer across ks (8 regs live)
            Frag a[2];
            a[0].f = *(const short8*)&h_lds[cur][(mt * 16 + cc) * HLDS_ST + q * 8];

            floatx4 acc[4];
            #pragma unroll
            for (int g = 0; g < 4; ++g) {
                const float bv = bias_r[g];
                acc[g] = (floatx4){bv, bv, bv, bv};
            }

            #pragma unroll
            for (int ks = 0; ks < KSTEPS; ++ks) {
                if (ks + 1 < KSTEPS) {
                    if (ks + 1 < 4)
                        a[(ks + 1) & 1].f = *(const short8*)
                            &h_lds[cur][(mt * 16 + cc) * HLDS_ST + (ks + 1) * 32 + q * 8];
                    else
                        a[(ks + 1) & 1].f = *(const short8*)
                            &x_lds[cur][(mt * 16 + cc) * XLDS_ST + q * 8];
                }
                #pragma unroll
                for (int g = 0; g < 4; ++g)
                    acc[g] = __builtin_amdgcn_mfma_f32_16x16x32_bf16(
                        a[ks & 1].f, bfr[g][ks].f, acc[g], 0, 0, 0);
            }

            // gates in-register: activations + c,h update (c in VGPRs)
            const int j = wv * 16 + cc;
            #pragma unroll
            for (int r = 0; r < 4; ++r) {
                const int mrow = mt * 16 + q * 4 + r;
                const float fv = sigm(acc[0][r]);
                const float iv = sigm(acc[1][r]);
                const float nv = tanh_f(acc[2][r]);
                const float ov = sigm(acc[3][r]);
                const float cn = c_st[mt][r] * fv + iv * nv;
                c_st[mt][r] = cn;
                const float hv = ov * tanh_f(cn);
                h_lds[cur ^ 1][mrow * HLDS_ST + j] = f2bf(hv);
                if (t == T_STEPS - 1) {
                    const size_t oi = (size_t)(b0 + mrow) * HDIM + j;
                    if constexpr (FP32) ((float*)out_)[oi] = hv;
                    else                ((unsigned short*)out_)[oi] = f2bf(hv);
                }
            }
        }
        __syncthreads();     // single barrier: publishes h[cur^1] and x[cur^1]
        cur ^= 1;
    }
}

extern "C" void kernel_launch(void* const* d_in, const int* in_sizes, int n_in,
                              void* d_out, int out_size, void* d_ws, size_t ws_size,
                              hipStream_t stream) {
    int* flag = (int*)d_ws;
    detect_dtype<<<dim3(1), dim3(64), 0, stream>>>((const unsigned short*)d_in[1], flag);

    pack_weights<false><<<dim3(320), dim3(256), 0, stream>>>(
        d_in[1], d_in[2], d_in[3], d_in[4], d_in[5], d_in[6], d_in[7], d_in[8], d_ws, flag);
    pack_weights<true><<<dim3(320), dim3(256), 0, stream>>>(
        d_in[1], d_in[2], d_in[3], d_in[4], d_in[5], d_in[6], d_in[7], d_in[8], d_ws, flag);

    lstm_fused<false><<<dim3(65536 / MB), dim3(512), 0, stream>>>(d_in[0], d_ws, d_out, flag);
    lstm_fused<true><<<dim3(65536 / MB), dim3(512), 0, stream>>>(d_in[0], d_ws, d_out, flag);
}

// Round 8
// 561.625 us; speedup vs baseline: 5.0278x; 5.0278x over previous
//
#include <hip/hip_runtime.h>
#include <stdint.h>

// LSTM: B=65536, T=28, IN=28, H=128. Final hidden [B,H] output.
// ROUND 8 = R6 structure (8-wave/512t blocks, wave owns 16 cols x 4 gates,
// 80 weight regs persistent, (512,4)) + VALU diet:
//  - c in REGISTERS (8/thread), LDS 22528 B
//  - weights PRE-SCALED by log2e (sigmoid gates) / 2log2e (candidate) ->
//    exp2 directly via __builtin_amdgcn_exp2f, no per-element mul
//  - bias folded into K-slot 156 (A-side constant 1.0 lives in the x_lds pad)
//    -> frees bias regs + addressing, keeps total ~128 regs/wave
// HW facts learned: per-SIMD unified VGPR pool = 512 regs -> (512,8) gives
// 64 regs/wave (R7: weights spilled, 9.9 GB scratch, 5x slower). 4 waves/SIMD
// at <=128 regs is the structural max with 80 persistent weight regs.
// Lessons: no volatile-asm reg pins (R5); weights persistent > L2 stream (R6).

#define T_STEPS   28
#define HDIM      128
#define KIN       156            // H + IN
#define MB        32             // batch rows per block
#define KSTEPS    5              // K=160: 4x32 (h) + 1x32 (x: 28 real + bias@28 + 3 pad)
#define HLDS_ST   136            // h_lds row stride in shorts (128 + 8 pad)
#define XLDS_ST   40             // x_lds row stride in shorts (32 + 8 pad)
#define L2E       1.4426950408889634f

#define WS_WOFF   1024           // byte offset of packed weights in d_ws

typedef __attribute__((ext_vector_type(8))) short  short8;
typedef __attribute__((ext_vector_type(4))) float  floatx4;

union Frag { short8 f; uint2 u2[2]; unsigned short s[8]; };
union Pk4  { uint2 u2; unsigned short s[4]; };

__device__ __forceinline__ float bf2f(unsigned short v) {
    union { uint32_t u; float f; } c; c.u = ((uint32_t)v) << 16; return c.f;
}
__device__ __forceinline__ unsigned short f2bf(float x) {
    union { float f; uint32_t u; } c; c.f = x;          // RNE bf16 (finite inputs)
    return (unsigned short)((c.u + 0x7FFFu + ((c.u >> 16) & 1u)) >> 16);
}
__device__ __forceinline__ float fast_rcp(float x) { return __builtin_amdgcn_rcpf(x); }
__device__ __forceinline__ float exp2_(float x)    { return __builtin_amdgcn_exp2f(x); }
// Inputs pre-scaled: sigm2 expects x' = log2e*x; tanh2 expects x'' = 2*log2e*x.
// NaN-free saturation: exp2(+inf)=inf -> rcp=0; exp2(-inf)=0 -> rcp(1)=1.
__device__ __forceinline__ float sigm2(float x)  { return fast_rcp(1.0f + exp2_(-x)); }
__device__ __forceinline__ float tanh2(float x)  { return 1.0f - 2.0f * fast_rcp(1.0f + exp2_(x)); }
__device__ __forceinline__ float tanh_c(float x) { return 1.0f - 2.0f * fast_rcp(1.0f + exp2_(2.0f * L2E * x)); }

// bf16 |W_f| <= 0.08 -> exponent field <= 123 always. fp32 read as shorts:
// mantissa halves ~uniform -> exponent field >= 127 with p~0.5/short.
__global__ void detect_dtype(const unsigned short* __restrict__ wf, int* __restrict__ flag) {
    const int lane = threadIdx.x;
    bool big = false;
    #pragma unroll
    for (int i = 0; i < 4; ++i) {
        unsigned e = (wf[lane * 4 + i] >> 7) & 0xFFu;
        if (e >= 127u) big = true;
    }
    const int isfp32 = __any(big) ? 1 : 0;
    if (lane == 0) *flag = isfp32;
}

// One-shot: pack W[4][128][156] -> bf16 per-(wave,ks,lane) fragments, values
// PRE-SCALED (f,i,o: *log2e; n: *2log2e). Bias (same scale) lands in K-slot
// 156 (ks=4,q=3,e=4); slots 157..159 zero.
//   chunk = wv*5+ks (2048 shorts); idx within: ln(6b) g(2b) e(3b)
//   value = SCALE[g] * W[g][wv*16 + (ln&15)][ks*32 + (ln>>4)*8 + e]
// Grid: 320 x 256 = 81920 shorts.
template <bool FP32>
__global__ void pack_weights(const void* __restrict__ Wf_, const void* __restrict__ bf_,
                             const void* __restrict__ Wi_, const void* __restrict__ bi_,
                             const void* __restrict__ Wc_, const void* __restrict__ bc_,
                             const void* __restrict__ Wo_, const void* __restrict__ bo_,
                             void* __restrict__ ws, const int* __restrict__ flag)
{
    if (*flag != (FP32 ? 1 : 0)) return;
    unsigned short* wpk = (unsigned short*)((char*)ws + WS_WOFF);

    const int gid = blockIdx.x * 256 + threadIdx.x;        // 0..81919
    const int e   = gid & 7;
    const int g   = (gid >> 3) & 3;
    const int ln  = (gid >> 5) & 63;
    const int blk = gid >> 11;                             // wv*5 + ks, 0..39
    const int ks  = blk % KSTEPS;
    const int wv  = blk / KSTEPS;
    const int n   = wv * 16 + (ln & 15);
    const int k   = ks * 32 + (ln >> 4) * 8 + e;
    const void* Wg = (g == 0) ? Wf_ : (g == 1) ? Wi_ : (g == 2) ? Wc_ : Wo_;
    const void* bg = (g == 0) ? bf_ : (g == 1) ? bi_ : (g == 2) ? bc_ : bo_;
    const float scale = (g == 2) ? 2.0f * L2E : L2E;

    unsigned short v = 0;
    if (k < KIN) {
        float w;
        if constexpr (FP32) w = ((const float*)Wg)[n * KIN + k];
        else                w = bf2f(((const unsigned short*)Wg)[n * KIN + k]);
        v = f2bf(w * scale);
    } else if (k == KIN) {                                  // bias slot (A=1.0)
        float b;
        if constexpr (FP32) b = ((const float*)bg)[n];
        else                b = bf2f(((const unsigned short*)bg)[n]);
        v = f2bf(b * scale);
    }
    wpk[gid] = v;
}

template <bool FP32>
__global__ __launch_bounds__(512, 4)
void lstm_fused(const void* __restrict__ x_, const void* __restrict__ ws,
                void* __restrict__ out_, const int* __restrict__ flag)
{
    if (*flag != (FP32 ? 1 : 0)) return;   // wrong-dtype variant: uniform exit

    __shared__ __align__(16) unsigned short h_lds[2][MB * HLDS_ST];   // 17408 B
    __shared__ __align__(16) unsigned short x_lds[2][MB * XLDS_ST];   //  5120 B

    const int tid  = threadIdx.x;
    const int wv   = tid >> 6;     // wave 0..7: owns output cols [16wv, 16wv+16)
    const int lane = tid & 63;
    const int q    = lane >> 4;    // quad
    const int cc   = lane & 15;
    const int b0   = blockIdx.x * MB;

    const unsigned short* wpk = (const unsigned short*)((const char*)ws + WS_WOFF);

    // ---- persistent weight B-fragments: 4 gates x 5 ks x 4 regs = 80.
    // Loaded once from L2 (20 x dwordx4 per thread); zero in-loop traffic.
    Frag bfr[4][KSTEPS];
    #pragma unroll
    for (int ks = 0; ks < KSTEPS; ++ks)
        #pragma unroll
        for (int g = 0; g < 4; ++g)
            bfr[g][ks].f = *(const short8*)(wpk + (size_t)(wv * KSTEPS + ks) * 2048
                                                + lane * 32 + g * 8);

    // zero h buf0 (h0=0); x pads: slot 28 = bf16(1.0) (bias A-column),
    // slots 29..39 = 0 forever.
    for (int i = tid; i < MB * HLDS_ST; i += 512) h_lds[0][i] = 0;
    for (int i = tid; i < MB * XLDS_ST; i += 512) {
        const unsigned short v = ((i % XLDS_ST) == 28) ? (unsigned short)0x3F80u
                                                       : (unsigned short)0u;
        x_lds[0][i] = v; x_lds[1][i] = v;
    }

    // x staging: 7 threads/row, 4 elems each -> 28 elems/row (224 of 512 threads)
    auto stage_x = [&](int ts, int buf) {
        if (tid < 224) {
            const int row = tid / 7, sub = tid % 7;
            const size_t off = (size_t)(b0 + row) * (T_STEPS * 28) + ts * 28 + sub * 4;
            Pk4 pk;
            if constexpr (FP32) {
                float4 v = *(const float4*)((const float*)x_ + off);
                pk.s[0] = f2bf(v.x); pk.s[1] = f2bf(v.y);
                pk.s[2] = f2bf(v.z); pk.s[3] = f2bf(v.w);
            } else {
                pk.u2 = *(const uint2*)((const unsigned short*)x_ + off);
            }
            *(uint2*)&x_lds[buf][row * XLDS_ST + sub * 4] = pk.u2;
        }
    };
    stage_x(0, 0);

    // ---- cell state in registers: thread owns col j = wv*16+cc, rows
    // mrow = mt*16 + q*4 + r -> c_st[mt][r], 8 VGPRs.
    float c_st[2][4];
    #pragma unroll
    for (int mt = 0; mt < 2; ++mt)
        #pragma unroll
        for (int r = 0; r < 4; ++r) c_st[mt][r] = 0.0f;

    __syncthreads();

    int cur = 0;
    #pragma unroll 1
    for (int t = 0; t < T_STEPS; ++t) {
        // prefetch next x tile into the other buffer (no reader until next step)
        if (t + 1 < T_STEPS) stage_x(t + 1, cur ^ 1);

        #pragma unroll
        for (int mt = 0; mt < 2; ++mt) {
            // A fragments: parity double-buffer across ks (8 regs live)
            Frag a[2];
            a[0].f = *(const short8*)&h_lds[cur][(mt * 16 + cc) * HLDS_ST + q * 8];

            floatx4 acc[4];
            #pragma unroll
            for (int g = 0; g < 4; ++g)
                acc[g] = (floatx4){0.0f, 0.0f, 0.0f, 0.0f};   // bias comes via K=156

            #pragma unroll
            for (int ks = 0; ks < KSTEPS; ++ks) {
                if (ks + 1 < KSTEPS) {
                    if (ks + 1 < 4)
                        a[(ks + 1) & 1].f = *(const short8*)
                            &h_lds[cur][(mt * 16 + cc) * HLDS_ST + (ks + 1) * 32 + q * 8];
                    else
                        a[(ks + 1) & 1].f = *(const short8*)
                            &x_lds[cur][(mt * 16 + cc) * XLDS_ST + q * 8];
                }
                #pragma unroll
                for (int g = 0; g < 4; ++g)
                    acc[g] = __builtin_amdgcn_mfma_f32_16x16x32_bf16(
                        a[ks & 1].f, bfr[g][ks].f, acc[g], 0, 0, 0);
            }

            // gates in-register: pre-activations are pre-scaled by log2e
            // (2log2e for n-gate) -> exp2 directly, no per-element scale mul.
            const int j = wv * 16 + cc;
            #pragma unroll
            for (int r = 0; r < 4; ++r) {
                const int mrow = mt * 16 + q * 4 + r;
                const float fv = sigm2(acc[0][r]);
                const float iv = sigm2(acc[1][r]);
                const float nv = tanh2(acc[2][r]);
                const float ov = sigm2(acc[3][r]);
                const float cn = fmaf(c_st[mt][r], fv, iv * nv);
                c_st[mt][r] = cn;
                const float hv = ov * tanh_c(cn);
                h_lds[cur ^ 1][mrow * HLDS_ST + j] = f2bf(hv);
                if (t == T_STEPS - 1) {
                    const size_t oi = (size_t)(b0 + mrow) * HDIM + j;
                    if constexpr (FP32) ((float*)out_)[oi] = hv;
                    else                ((unsigned short*)out_)[oi] = f2bf(hv);
                }
            }
        }
        __syncthreads();     // single barrier: publishes h[cur^1] and x[cur^1]
        cur ^= 1;
    }
}

extern "C" void kernel_launch(void* const* d_in, const int* in_sizes, int n_in,
                              void* d_out, int out_size, void* d_ws, size_t ws_size,
                              hipStream_t stream) {
    int* flag = (int*)d_ws;
    detect_dtype<<<dim3(1), dim3(64), 0, stream>>>((const unsigned short*)d_in[1], flag);

    pack_weights<false><<<dim3(320), dim3(256), 0, stream>>>(
        d_in[1], d_in[2], d_in[3], d_in[4], d_in[5], d_in[6], d_in[7], d_in[8], d_ws, flag);
    pack_weights<true><<<dim3(320), dim3(256), 0, stream>>>(
        d_in[1], d_in[2], d_in[3], d_in[4], d_in[5], d_in[6], d_in[7], d_in[8], d_ws, flag);

    lstm_fused<false><<<dim3(65536 / MB), dim3(512), 0, stream>>>(d_in[0], d_ws, d_out, flag);
    lstm_fused<true><<<dim3(65536 / MB), dim3(512), 0, stream>>>(d_in[0], d_ws, d_out, flag);
}